// Round 11
// baseline (228.332 us; speedup 1.0000x reference)
//
#include <hip/hip_runtime.h>
#include <hip/hip_bf16.h>
#include <stdint.h>

// ---------------------------------------------------------------------------
// Per-type MLP dispatch (ElemwiseModels): out[n] = MLP_{elems[n]}(desc[n])
//   L1: h1 = tanh(x @ W1[t] + b1[t])     x:256 -> 256
//   L2: h2 = tanh(h1 @ W2[t] + b2[t])    256 -> 256
//   L3: out = h2 . W3[t] + b3[t]         256 -> 1
// r10: r9 barrier-free structure with the L3 epilogue FIXED: acc2[q][r] is
// C2[atom = g*4+r][kout = q*16 + a16]  (C/D: col=lane&15, row=(lane>>4)*4+r).
// Each wave owns 16 atoms end-to-end; x global->B-frag direct; h1 in a
// private 8 KB LDS region; no __syncthreads in mlp_k.
// ---------------------------------------------------------------------------

typedef __attribute__((ext_vector_type(8))) short short8;   // 8 x bf16 frag
typedef __attribute__((ext_vector_type(4))) float f32x4;    // MFMA acc

#define NPB 256          // partition blocks
#define NTY 4            // types

__device__ __forceinline__ unsigned short f2bf(float f) {
    union { float f; uint32_t u; } v; v.f = f;
    uint32_t u = v.u;
    uint32_t r = (u + 0x7FFFu + ((u >> 16) & 1u)) >> 16;   // RN-even
    return (unsigned short)r;
}
__device__ __forceinline__ float fast_tanh(float x) {
    x = fminf(fmaxf(x, -10.0f), 10.0f);
    float e = __expf(2.0f * x);
    return (e - 1.0f) * __builtin_amdgcn_rcpf(e + 1.0f);
}

// ---------------- ws layout -------------------------------------------------
// hdr   (32 ints @ 0):      [0..3] counts, [8..11] base, [12..15] tilebase, [16] total tiles
// counts(4*NPB ints @128);  cursor(4*NPB ints);  sorted(n ints);  w1s/w2s (bf16)
// ---------------------------------------------------------------------------

__global__ void count_k(const int* __restrict__ elems, int n, int chunk,
                        int* __restrict__ counts) {
    __shared__ int h[NTY];
    if (threadIdx.x < NTY) h[threadIdx.x] = 0;
    __syncthreads();
    const int start = blockIdx.x * chunk;
    const int end   = min(start + chunk, n);
    for (int i = start + threadIdx.x; i < end; i += blockDim.x)
        atomicAdd(&h[elems[i]], 1);
    __syncthreads();
    if (threadIdx.x < NTY) counts[threadIdx.x * NPB + blockIdx.x] = h[threadIdx.x];
}

__global__ void prefix_k(const int* __restrict__ counts,
                         int* __restrict__ cursor, int* __restrict__ hdr) {
    __shared__ int tot[NTY];
    const int t = threadIdx.x;
    if (t < NTY) {
        int s = 0;
        for (int b = 0; b < NPB; ++b) s += counts[t * NPB + b];
        tot[t] = s;
    }
    __syncthreads();
    if (t == 0) {
        int b = 0, tb = 0;
        for (int ty = 0; ty < NTY; ++ty) {
            hdr[ty]      = tot[ty];
            hdr[8 + ty]  = b;
            hdr[12 + ty] = tb;
            b  += tot[ty];
            tb += (tot[ty] + 63) >> 6;
        }
        hdr[16] = tb;
    }
    __syncthreads();
    if (t < NTY) {
        int run = hdr[8 + t];
        for (int b = 0; b < NPB; ++b) {
            cursor[t * NPB + b] = run;
            run += counts[t * NPB + b];
        }
    }
}

__global__ void scatter_k(const int* __restrict__ elems, int n, int chunk,
                          const int* __restrict__ cursor, int* __restrict__ sorted) {
    __shared__ int cur[NTY];
    if (threadIdx.x < NTY) cur[threadIdx.x] = cursor[threadIdx.x * NPB + blockIdx.x];
    __syncthreads();
    const int start = blockIdx.x * chunk;
    const int end   = min(start + chunk, n);
    for (int i = start + threadIdx.x; i < end; i += blockDim.x) {
        int ty  = elems[i];
        int pos = atomicAdd(&cur[ty], 1);   // LDS atomic: block-local
        sorted[pos] = i;
    }
}

// Pre-swizzle W1,W2 (fp32 [t][din][dout]) into bf16 MFMA-frag order:
// frag(t,tile,ks): 64 lanes x 16B contiguous; lane l elem j =
//   W[t][ks*32 + (l>>4)*8 + j][tile*16 + (l&15)]
__global__ void wconv_k(const float* __restrict__ W1, const float* __restrict__ W2,
                        unsigned short* __restrict__ w1s, unsigned short* __restrict__ w2s) {
    int gid  = blockIdx.x * blockDim.x + threadIdx.x;   // 0..65535
    int lane = gid & 63;
    int ks   = (gid >> 6) & 7;
    int tile = (gid >> 9) & 15;
    int t    = (gid >> 13) & 3;
    int layer = gid >> 15;
    const float* W = layer ? W2 : W1;
    unsigned short* o = layer ? w2s : w1s;
    int dbase = ks * 32 + ((lane >> 4) << 3);
    int col   = tile * 16 + (lane & 15);
    unsigned short v[8];
#pragma unroll
    for (int j = 0; j < 8; ++j)
        v[j] = f2bf(W[(size_t)t * 65536 + (size_t)(dbase + j) * 256 + col]);
    unsigned short* dst = o + ((size_t)(t * 16 + tile) * 8 + ks) * 512 + lane * 8;
    *(short8*)dst = *(short8*)v;
}

// ---------------------------------------------------------------------------
// Main fused MLP kernel: 4 waves/block, each wave owns 16 atoms end-to-end.
// No __syncthreads. LDS = 32 KB (4 x 8 KB private h1 regions).
// ---------------------------------------------------------------------------
__global__ __launch_bounds__(256, 4) void mlp_k(
    const float* __restrict__ desc,
    const float* __restrict__ b1g,
    const float* __restrict__ b2g,
    const float* __restrict__ W3,
    const float* __restrict__ b3,
    const int* __restrict__ hdr,
    const int* __restrict__ sorted,
    const unsigned short* __restrict__ w1s,
    const unsigned short* __restrict__ w2s,
    float* __restrict__ out)
{
    __shared__ __align__(16) char h1lds[32768];   // wave w: [w*8192, (w+1)*8192)

    const int tid  = threadIdx.x;
    const int lane = tid & 63;
    const int w    = tid >> 6;
    const int a16  = lane & 15;      // atom slot within wave (input rows)
    const int g    = lane >> 4;      // k-group 0..3

    const int total = hdr[16];
    const int b = blockIdx.x;
    if (b >= total) return;

    int t = 3;
    if      (b < hdr[13]) t = 0;
    else if (b < hdr[14]) t = 1;
    else if (b < hdr[15]) t = 2;
    const int tloc   = b - hdr[12 + t];
    const int cnt    = hdr[t];
    const int base   = hdr[8 + t];
    const int astart = tloc * 64;

    const int am     = astart + w * 16 + a16;         // my atom within type
    const bool valid = (am < cnt);
    const int idx    = valid ? sorted[base + am] : 0; // safe fallback row
    const float* xrow = desc + (size_t)idx * 256;

    const unsigned short* w1t = w1s + (size_t)t * (16 * 8 * 512);
    const unsigned short* w2t = w2s + (size_t)t * (16 * 8 * 512);

    // ---- layer 1: C1[h][atom]; this wave: 16 h-tiles x its one atom-tile
    f32x4 acc[16];
#pragma unroll
    for (int q = 0; q < 16; ++q) acc[q] = (f32x4){0.f, 0.f, 0.f, 0.f};

#pragma unroll
    for (int ks = 0; ks < 8; ++ks) {
        // B-frag direct from global: x[a16][ks*32 + g*8 + j], j=0..7
        const float4 v0 = *(const float4*)(xrow + ks * 32 + g * 8);
        const float4 v1 = *(const float4*)(xrow + ks * 32 + g * 8 + 4);
        union { short8 s; __hip_bfloat162 h[4]; } bu;
        bu.h[0] = __float22bfloat162_rn(make_float2(v0.x, v0.y));
        bu.h[1] = __float22bfloat162_rn(make_float2(v0.z, v0.w));
        bu.h[2] = __float22bfloat162_rn(make_float2(v1.x, v1.y));
        bu.h[3] = __float22bfloat162_rn(make_float2(v1.z, v1.w));
#pragma unroll
        for (int q = 0; q < 16; ++q) {
            const short8 af = *(const short8*)(w1t + ((size_t)(q * 8 + ks)) * 512 + lane * 8);
            acc[q] = __builtin_amdgcn_mfma_f32_16x16x32_bf16(af, bu.s, acc[q], 0, 0, 0);
        }
    }

    // ---- ep1: bias + tanh -> bf16 h1 into private LDS (swizzled)
    // C1: col=lane&15=atom a16, row=(lane>>4)*4+r = h within tile q.
    // lane writes h = q*16 + g*4 + r for its atom a16 (8 B per q).
    char* myh1 = h1lds + w * 8192;
#pragma unroll
    for (int q = 0; q < 16; ++q) {
        const float4 bb = *(const float4*)(b1g + t * 256 + q * 16 + g * 4);
        const float z0 = fast_tanh(acc[q][0] + bb.x);
        const float z1 = fast_tanh(acc[q][1] + bb.y);
        const float z2 = fast_tanh(acc[q][2] + bb.z);
        const float z3 = fast_tanh(acc[q][3] + bb.w);
        union { uint64_t u; __hip_bfloat162 h[2]; } hw;
        hw.h[0] = __float22bfloat162_rn(make_float2(z0, z1));
        hw.h[1] = __float22bfloat162_rn(make_float2(z2, z3));
        const int off = a16 * 512 + ((q * 32 + g * 8) ^ ((a16 & 7) << 4));
        *(uint64_t*)(myh1 + off) = hw.u;
    }
    // wave-private LDS: same-wave DS ordering + compiler lgkmcnt (no barrier)

    // ---- layer 2: C2[atom][kout] = h1(A) * W2t(B); 16 kout-tiles
    f32x4 acc2[16];
#pragma unroll
    for (int q = 0; q < 16; ++q) acc2[q] = (f32x4){0.f, 0.f, 0.f, 0.f};

#pragma unroll
    for (int ks = 0; ks < 8; ++ks) {
        // A-frag: h1[a16][ks*32 + g*8 + j] -> bytes ks*64 + g*16, same XOR
        const int off = a16 * 512 + ((ks * 64 + g * 16) ^ ((a16 & 7) << 4));
        const short8 ah = *(const short8*)(myh1 + off);
#pragma unroll
        for (int q = 0; q < 16; ++q) {
            const short8 bw = *(const short8*)(w2t + ((size_t)(q * 8 + ks)) * 512 + lane * 8);
            acc2[q] = __builtin_amdgcn_mfma_f32_16x16x32_bf16(ah, bw, acc2[q], 0, 0, 0);
        }
    }

    // ---- layer 3 (FIXED mapping): acc2[q][r] = C2[atom=g*4+r][kout=q*16+a16]
    float psum[4] = {0.f, 0.f, 0.f, 0.f};
#pragma unroll
    for (int q = 0; q < 16; ++q) {
        const int kout = q * 16 + a16;
        const float b2v = b2g[t * 256 + kout];
        const float w3v = W3[t * 256 + kout];
#pragma unroll
        for (int r = 0; r < 4; ++r)
            psum[r] += fast_tanh(acc2[q][r] + b2v) * w3v;
    }
    // reduce over the 16 kout-lanes within each g-group
#pragma unroll
    for (int m = 1; m <= 8; m <<= 1)
#pragma unroll
        for (int r = 0; r < 4; ++r)
            psum[r] += __shfl_xor(psum[r], m, 64);

    if (a16 == 0) {
        const float b3v = b3[t];
#pragma unroll
        for (int r = 0; r < 4; ++r) {
            const int am2 = astart + w * 16 + g * 4 + r;   // atom = g*4+r
            if (am2 < cnt)
                out[sorted[base + am2]] = psum[r] + b3v;
        }
    }
}

extern "C" void kernel_launch(void* const* d_in, const int* in_sizes, int n_in,
                              void* d_out, int out_size, void* d_ws, size_t ws_size,
                              hipStream_t stream) {
    const float* desc = (const float*)d_in[0];
    const int*   elems = (const int*)d_in[1];
    const float* W1 = (const float*)d_in[2];
    const float* b1 = (const float*)d_in[3];
    const float* W2 = (const float*)d_in[4];
    const float* b2 = (const float*)d_in[5];
    const float* W3 = (const float*)d_in[6];
    const float* b3 = (const float*)d_in[7];
    float* out = (float*)d_out;
    const int n = in_sizes[1];   // N_ATOMS

    char* ws = (char*)d_ws;
    int* hdr    = (int*)ws;                       // 32 ints
    int* counts = (int*)(ws + 128);               // 4*NPB ints
    int* cursor = (int*)(ws + 128 + 4 * NPB * 4); // 4*NPB ints
    int* sorted = (int*)(ws + 128 + 8 * NPB * 4);
    unsigned short* w1s = (unsigned short*)((char*)sorted + (size_t)n * 4);
    unsigned short* w2s = w1s + (size_t)4 * 16 * 8 * 512;

    const int chunk = (n + NPB - 1) / NPB;

    count_k<<<NPB, 256, 0, stream>>>(elems, n, chunk, counts);
    prefix_k<<<1, 64, 0, stream>>>(counts, cursor, hdr);
    scatter_k<<<NPB, 256, 0, stream>>>(elems, n, chunk, cursor, sorted);
    wconv_k<<<256, 256, 0, stream>>>(W1, W2, w1s, w2s);

    const int maxtiles = (n >> 6) + 4;
    mlp_k<<<maxtiles, 256, 0, stream>>>(desc, b1, b2, W3, b3,
                                        hdr, sorted, w1s, w2s, out);
}

// Round 12
// 194.510 us; speedup vs baseline: 1.1739x; 1.1739x over previous
//
#include <hip/hip_runtime.h>
#include <hip/hip_bf16.h>
#include <stdint.h>

// ---------------------------------------------------------------------------
// Per-type MLP dispatch (ElemwiseModels): out[n] = MLP_{elems[n]}(desc[n])
//   L1: h1 = tanh(x @ W1[t] + b1[t])     x:256 -> 256
//   L2: h2 = tanh(h1 @ W2[t] + b2[t])    256 -> 256
//   L3: out = h2 . W3[t] + b3[t]         256 -> 1
// r12: r11 barrier-free structure with the VGPR SPILL FIXED:
//   - L1/L2 processed in two halves of 8 tiles (acc[8] not acc[16])
//   - x kept in registers as 8 pre-converted bf16 B-frags (bu[8])
//   - __launch_bounds__(256,2) so the allocator isn't squeezed to 64 VGPR
// Each wave owns 16 atoms end-to-end; h1 in a private 8 KB LDS region;
// no __syncthreads in mlp_k. L3 mapping r11-validated.
// ---------------------------------------------------------------------------

typedef __attribute__((ext_vector_type(8))) short short8;   // 8 x bf16 frag
typedef __attribute__((ext_vector_type(4))) float f32x4;    // MFMA acc

#define NPB 256          // partition blocks
#define NTY 4            // types

__device__ __forceinline__ unsigned short f2bf(float f) {
    union { float f; uint32_t u; } v; v.f = f;
    uint32_t u = v.u;
    uint32_t r = (u + 0x7FFFu + ((u >> 16) & 1u)) >> 16;   // RN-even
    return (unsigned short)r;
}
__device__ __forceinline__ float fast_tanh(float x) {
    x = fminf(fmaxf(x, -10.0f), 10.0f);
    float e = __expf(2.0f * x);
    return (e - 1.0f) * __builtin_amdgcn_rcpf(e + 1.0f);
}

// ---------------- ws layout -------------------------------------------------
// hdr   (32 ints @ 0):      [0..3] counts, [8..11] base, [12..15] tilebase, [16] total tiles
// counts(4*NPB ints @128);  cursor(4*NPB ints);  sorted(n ints);  w1s/w2s (bf16)
// ---------------------------------------------------------------------------

__global__ void count_k(const int* __restrict__ elems, int n, int chunk,
                        int* __restrict__ counts) {
    __shared__ int h[NTY];
    if (threadIdx.x < NTY) h[threadIdx.x] = 0;
    __syncthreads();
    const int start = blockIdx.x * chunk;
    const int end   = min(start + chunk, n);
    for (int i = start + threadIdx.x; i < end; i += blockDim.x)
        atomicAdd(&h[elems[i]], 1);
    __syncthreads();
    if (threadIdx.x < NTY) counts[threadIdx.x * NPB + blockIdx.x] = h[threadIdx.x];
}

__global__ void prefix_k(const int* __restrict__ counts,
                         int* __restrict__ cursor, int* __restrict__ hdr) {
    __shared__ int tot[NTY];
    const int t = threadIdx.x;
    if (t < NTY) {
        int s = 0;
        for (int b = 0; b < NPB; ++b) s += counts[t * NPB + b];
        tot[t] = s;
    }
    __syncthreads();
    if (t == 0) {
        int b = 0, tb = 0;
        for (int ty = 0; ty < NTY; ++ty) {
            hdr[ty]      = tot[ty];
            hdr[8 + ty]  = b;
            hdr[12 + ty] = tb;
            b  += tot[ty];
            tb += (tot[ty] + 63) >> 6;
        }
        hdr[16] = tb;
    }
    __syncthreads();
    if (t < NTY) {
        int run = hdr[8 + t];
        for (int b = 0; b < NPB; ++b) {
            cursor[t * NPB + b] = run;
            run += counts[t * NPB + b];
        }
    }
}

__global__ void scatter_k(const int* __restrict__ elems, int n, int chunk,
                          const int* __restrict__ cursor, int* __restrict__ sorted) {
    __shared__ int cur[NTY];
    if (threadIdx.x < NTY) cur[threadIdx.x] = cursor[threadIdx.x * NPB + blockIdx.x];
    __syncthreads();
    const int start = blockIdx.x * chunk;
    const int end   = min(start + chunk, n);
    for (int i = start + threadIdx.x; i < end; i += blockDim.x) {
        int ty  = elems[i];
        int pos = atomicAdd(&cur[ty], 1);   // LDS atomic: block-local
        sorted[pos] = i;
    }
}

// Pre-swizzle W1,W2 (fp32 [t][din][dout]) into bf16 MFMA-frag order:
// frag(t,tile,ks): 64 lanes x 16B contiguous; lane l elem j =
//   W[t][ks*32 + (l>>4)*8 + j][tile*16 + (l&15)]
__global__ void wconv_k(const float* __restrict__ W1, const float* __restrict__ W2,
                        unsigned short* __restrict__ w1s, unsigned short* __restrict__ w2s) {
    int gid  = blockIdx.x * blockDim.x + threadIdx.x;   // 0..65535
    int lane = gid & 63;
    int ks   = (gid >> 6) & 7;
    int tile = (gid >> 9) & 15;
    int t    = (gid >> 13) & 3;
    int layer = gid >> 15;
    const float* W = layer ? W2 : W1;
    unsigned short* o = layer ? w2s : w1s;
    int dbase = ks * 32 + ((lane >> 4) << 3);
    int col   = tile * 16 + (lane & 15);
    unsigned short v[8];
#pragma unroll
    for (int j = 0; j < 8; ++j)
        v[j] = f2bf(W[(size_t)t * 65536 + (size_t)(dbase + j) * 256 + col]);
    unsigned short* dst = o + ((size_t)(t * 16 + tile) * 8 + ks) * 512 + lane * 8;
    *(short8*)dst = *(short8*)v;
}

// ---------------------------------------------------------------------------
// Main fused MLP kernel: 4 waves/block, each wave owns 16 atoms end-to-end.
// No __syncthreads. LDS = 32 KB (4 x 8 KB private h1 regions).
// Halved accumulator live-range to avoid spill (r11 lesson).
// ---------------------------------------------------------------------------
__global__ __launch_bounds__(256, 2) void mlp_k(
    const float* __restrict__ desc,
    const float* __restrict__ b1g,
    const float* __restrict__ b2g,
    const float* __restrict__ W3,
    const float* __restrict__ b3,
    const int* __restrict__ hdr,
    const int* __restrict__ sorted,
    const unsigned short* __restrict__ w1s,
    const unsigned short* __restrict__ w2s,
    float* __restrict__ out)
{
    __shared__ __align__(16) char h1lds[32768];   // wave w: [w*8192, (w+1)*8192)

    const int tid  = threadIdx.x;
    const int lane = tid & 63;
    const int w    = tid >> 6;
    const int a16  = lane & 15;      // atom slot within wave (input rows)
    const int g    = lane >> 4;      // k-group 0..3

    const int total = hdr[16];
    const int b = blockIdx.x;
    if (b >= total) return;

    int t = 3;
    if      (b < hdr[13]) t = 0;
    else if (b < hdr[14]) t = 1;
    else if (b < hdr[15]) t = 2;
    const int tloc   = b - hdr[12 + t];
    const int cnt    = hdr[t];
    const int base   = hdr[8 + t];
    const int astart = tloc * 64;

    const int am     = astart + w * 16 + a16;         // my atom within type
    const bool valid = (am < cnt);
    const int idx    = valid ? sorted[base + am] : 0; // safe fallback row
    const float* xrow = desc + (size_t)idx * 256;

    const unsigned short* w1t = w1s + (size_t)t * (16 * 8 * 512);
    const unsigned short* w2t = w2s + (size_t)t * (16 * 8 * 512);

    // ---- load + convert x once: 8 B-frags held in registers (32 VGPRs)
    short8 bu[8];
#pragma unroll
    for (int ks = 0; ks < 8; ++ks) {
        const float4 v0 = *(const float4*)(xrow + ks * 32 + g * 8);
        const float4 v1 = *(const float4*)(xrow + ks * 32 + g * 8 + 4);
        union { short8 s; __hip_bfloat162 h[4]; } u;
        u.h[0] = __float22bfloat162_rn(make_float2(v0.x, v0.y));
        u.h[1] = __float22bfloat162_rn(make_float2(v0.z, v0.w));
        u.h[2] = __float22bfloat162_rn(make_float2(v1.x, v1.y));
        u.h[3] = __float22bfloat162_rn(make_float2(v1.z, v1.w));
        bu[ks] = u.s;
    }

    char* myh1 = h1lds + w * 8192;

    // ---- layer 1 + ep1, two halves of 8 h-tiles (acc[8] live, not 16)
#pragma unroll
    for (int half = 0; half < 2; ++half) {
        f32x4 acc[8];
#pragma unroll
        for (int q8 = 0; q8 < 8; ++q8) acc[q8] = (f32x4){0.f, 0.f, 0.f, 0.f};

#pragma unroll
        for (int ks = 0; ks < 8; ++ks) {
#pragma unroll
            for (int q8 = 0; q8 < 8; ++q8) {
                const int q = half * 8 + q8;
                const short8 af = *(const short8*)(w1t + ((size_t)(q * 8 + ks)) * 512 + lane * 8);
                acc[q8] = __builtin_amdgcn_mfma_f32_16x16x32_bf16(af, bu[ks], acc[q8], 0, 0, 0);
            }
        }
        // ep1: C1 col=a16 (atom), row=g*4+r (h within tile q); write 8 B per q
#pragma unroll
        for (int q8 = 0; q8 < 8; ++q8) {
            const int q = half * 8 + q8;
            const float4 bb = *(const float4*)(b1g + t * 256 + q * 16 + g * 4);
            const float z0 = fast_tanh(acc[q8][0] + bb.x);
            const float z1 = fast_tanh(acc[q8][1] + bb.y);
            const float z2 = fast_tanh(acc[q8][2] + bb.z);
            const float z3 = fast_tanh(acc[q8][3] + bb.w);
            union { uint64_t u; __hip_bfloat162 h[2]; } hw;
            hw.h[0] = __float22bfloat162_rn(make_float2(z0, z1));
            hw.h[1] = __float22bfloat162_rn(make_float2(z2, z3));
            const int off = a16 * 512 + ((q * 32 + g * 8) ^ ((a16 & 7) << 4));
            *(uint64_t*)(myh1 + off) = hw.u;
        }
    }
    // wave-private LDS: same-wave DS ordering + compiler lgkmcnt (no barrier)

    // ---- layer 2 + ep2/L3, two halves of 8 kout-tiles (acc2[8] live)
    float psum[4] = {0.f, 0.f, 0.f, 0.f};
#pragma unroll
    for (int half = 0; half < 2; ++half) {
        f32x4 acc2[8];
#pragma unroll
        for (int q8 = 0; q8 < 8; ++q8) acc2[q8] = (f32x4){0.f, 0.f, 0.f, 0.f};

#pragma unroll
        for (int ks = 0; ks < 8; ++ks) {
            // A-frag: h1[a16][ks*32 + g*8 + j] -> bytes ks*64 + g*16, same XOR
            const int off = a16 * 512 + ((ks * 64 + g * 16) ^ ((a16 & 7) << 4));
            const short8 ah = *(const short8*)(myh1 + off);
#pragma unroll
            for (int q8 = 0; q8 < 8; ++q8) {
                const int q = half * 8 + q8;
                const short8 bw = *(const short8*)(w2t + ((size_t)(q * 8 + ks)) * 512 + lane * 8);
                acc2[q8] = __builtin_amdgcn_mfma_f32_16x16x32_bf16(ah, bw, acc2[q8], 0, 0, 0);
            }
        }
        // acc2[q8][r] = C2[atom=g*4+r][kout=(half*8+q8)*16 + a16]  (r11-validated)
#pragma unroll
        for (int q8 = 0; q8 < 8; ++q8) {
            const int kout = (half * 8 + q8) * 16 + a16;
            const float b2v = b2g[t * 256 + kout];
            const float w3v = W3[t * 256 + kout];
#pragma unroll
            for (int r = 0; r < 4; ++r)
                psum[r] += fast_tanh(acc2[q8][r] + b2v) * w3v;
        }
    }

    // reduce over the 16 kout-lanes within each g-group
#pragma unroll
    for (int m = 1; m <= 8; m <<= 1)
#pragma unroll
        for (int r = 0; r < 4; ++r)
            psum[r] += __shfl_xor(psum[r], m, 64);

    if (a16 == 0) {
        const float b3v = b3[t];
#pragma unroll
        for (int r = 0; r < 4; ++r) {
            const int am2 = astart + w * 16 + g * 4 + r;   // atom = g*4+r
            if (am2 < cnt)
                out[sorted[base + am2]] = psum[r] + b3v;
        }
    }
}

extern "C" void kernel_launch(void* const* d_in, const int* in_sizes, int n_in,
                              void* d_out, int out_size, void* d_ws, size_t ws_size,
                              hipStream_t stream) {
    const float* desc = (const float*)d_in[0];
    const int*   elems = (const int*)d_in[1];
    const float* W1 = (const float*)d_in[2];
    const float* b1 = (const float*)d_in[3];
    const float* W2 = (const float*)d_in[4];
    const float* b2 = (const float*)d_in[5];
    const float* W3 = (const float*)d_in[6];
    const float* b3 = (const float*)d_in[7];
    float* out = (float*)d_out;
    const int n = in_sizes[1];   // N_ATOMS

    char* ws = (char*)d_ws;
    int* hdr    = (int*)ws;                       // 32 ints
    int* counts = (int*)(ws + 128);               // 4*NPB ints
    int* cursor = (int*)(ws + 128 + 4 * NPB * 4); // 4*NPB ints
    int* sorted = (int*)(ws + 128 + 8 * NPB * 4);
    unsigned short* w1s = (unsigned short*)((char*)sorted + (size_t)n * 4);
    unsigned short* w2s = w1s + (size_t)4 * 16 * 8 * 512;

    const int chunk = (n + NPB - 1) / NPB;

    count_k<<<NPB, 256, 0, stream>>>(elems, n, chunk, counts);
    prefix_k<<<1, 64, 0, stream>>>(counts, cursor, hdr);
    scatter_k<<<NPB, 256, 0, stream>>>(elems, n, chunk, cursor, sorted);
    wconv_k<<<256, 256, 0, stream>>>(W1, W2, w1s, w2s);

    const int maxtiles = (n >> 6) + 4;
    mlp_k<<<maxtiles, 256, 0, stream>>>(desc, b1, b2, W3, b3,
                                        hdr, sorted, w1s, w2s, out);
}

// Round 13
// 179.891 us; speedup vs baseline: 1.2693x; 1.0813x over previous
//
#include <hip/hip_runtime.h>
#include <hip/hip_bf16.h>
#include <stdint.h>

// ---------------------------------------------------------------------------
// Per-type MLP dispatch (ElemwiseModels): out[n] = MLP_{elems[n]}(desc[n])
//   L1: h1 = tanh(x @ W1[t] + b1[t])     x:256 -> 256
//   L2: h2 = tanh(h1 @ W2[t] + b2[t])    256 -> 256
//   L3: out = h2 . W3[t] + b3[t]         256 -> 1
// r13: PERSISTENT DOUBLE-BUFFERED block-cooperative kernel.
//  - grid=512 (2 blocks/CU); each block loops over ~4 tiles of 64 atoms
//  - T14 async stage: next tile's x issued into regs BEFORE compute,
//    converted+written to the other LDS buffer AFTER compute
//  - block-cooperative L1/L2 (r8-validated fragments): 4x weight reuse
//  - plain bf16 activations (absmax pinned by weight rounding, r8)
// ---------------------------------------------------------------------------

typedef __attribute__((ext_vector_type(8))) short short8;   // 8 x bf16 frag
typedef __attribute__((ext_vector_type(4))) float f32x4;    // MFMA acc

#define NPB 256          // partition blocks
#define NTY 4            // types
#define MLPGRID 512      // persistent mlp blocks (2 per CU)

__device__ __forceinline__ unsigned short f2bf(float f) {
    union { float f; uint32_t u; } v; v.f = f;
    uint32_t u = v.u;
    uint32_t r = (u + 0x7FFFu + ((u >> 16) & 1u)) >> 16;   // RN-even
    return (unsigned short)r;
}
__device__ __forceinline__ float fast_tanh(float x) {
    x = fminf(fmaxf(x, -10.0f), 10.0f);
    float e = __expf(2.0f * x);
    return (e - 1.0f) * __builtin_amdgcn_rcpf(e + 1.0f);
}

// ---------------- ws layout -------------------------------------------------
// hdr   (32 ints @ 0):      [0..3] counts, [8..11] base, [12..15] tilebase, [16] total tiles
// counts(4*NPB ints @128);  cursor(4*NPB ints);  sorted(n ints);  w1s/w2s (bf16)
// ---------------------------------------------------------------------------

__global__ void count_k(const int* __restrict__ elems, int n, int chunk,
                        int* __restrict__ counts) {
    __shared__ int h[NTY];
    if (threadIdx.x < NTY) h[threadIdx.x] = 0;
    __syncthreads();
    const int start = blockIdx.x * chunk;
    const int end   = min(start + chunk, n);
    for (int i = start + threadIdx.x; i < end; i += blockDim.x)
        atomicAdd(&h[elems[i]], 1);
    __syncthreads();
    if (threadIdx.x < NTY) counts[threadIdx.x * NPB + blockIdx.x] = h[threadIdx.x];
}

__global__ void prefix_k(const int* __restrict__ counts,
                         int* __restrict__ cursor, int* __restrict__ hdr) {
    __shared__ int tot[NTY];
    const int t = threadIdx.x;
    if (t < NTY) {
        int s = 0;
        for (int b = 0; b < NPB; ++b) s += counts[t * NPB + b];
        tot[t] = s;
    }
    __syncthreads();
    if (t == 0) {
        int b = 0, tb = 0;
        for (int ty = 0; ty < NTY; ++ty) {
            hdr[ty]      = tot[ty];
            hdr[8 + ty]  = b;
            hdr[12 + ty] = tb;
            b  += tot[ty];
            tb += (tot[ty] + 63) >> 6;
        }
        hdr[16] = tb;
    }
    __syncthreads();
    if (t < NTY) {
        int run = hdr[8 + t];
        for (int b = 0; b < NPB; ++b) {
            cursor[t * NPB + b] = run;
            run += counts[t * NPB + b];
        }
    }
}

__global__ void scatter_k(const int* __restrict__ elems, int n, int chunk,
                          const int* __restrict__ cursor, int* __restrict__ sorted) {
    __shared__ int cur[NTY];
    if (threadIdx.x < NTY) cur[threadIdx.x] = cursor[threadIdx.x * NPB + blockIdx.x];
    __syncthreads();
    const int start = blockIdx.x * chunk;
    const int end   = min(start + chunk, n);
    for (int i = start + threadIdx.x; i < end; i += blockDim.x) {
        int ty  = elems[i];
        int pos = atomicAdd(&cur[ty], 1);   // LDS atomic: block-local
        sorted[pos] = i;
    }
}

// Pre-swizzle W1,W2 (fp32 [t][din][dout]) into bf16 MFMA-frag order:
// frag(t,tile,ks): 64 lanes x 16B contiguous; lane l elem j =
//   W[t][ks*32 + (l>>4)*8 + j][tile*16 + (l&15)]
__global__ void wconv_k(const float* __restrict__ W1, const float* __restrict__ W2,
                        unsigned short* __restrict__ w1s, unsigned short* __restrict__ w2s) {
    int gid  = blockIdx.x * blockDim.x + threadIdx.x;   // 0..65535
    int lane = gid & 63;
    int ks   = (gid >> 6) & 7;
    int tile = (gid >> 9) & 15;
    int t    = (gid >> 13) & 3;
    int layer = gid >> 15;
    const float* W = layer ? W2 : W1;
    unsigned short* o = layer ? w2s : w1s;
    int dbase = ks * 32 + ((lane >> 4) << 3);
    int col   = tile * 16 + (lane & 15);
    unsigned short v[8];
#pragma unroll
    for (int j = 0; j < 8; ++j)
        v[j] = f2bf(W[(size_t)t * 65536 + (size_t)(dbase + j) * 256 + col]);
    unsigned short* dst = o + ((size_t)(t * 16 + tile) * 8 + ks) * 512 + lane * 8;
    *(short8*)dst = *(short8*)v;
}

// ---------------------------------------------------------------------------
// Persistent main kernel: 512 blocks, each loops over tiles bid, bid+512, ...
// LDS: buf[2][32KB] (x/h1 double buffer) + part = 66.5 KB -> 2 blocks/CU.
// ---------------------------------------------------------------------------
__global__ __launch_bounds__(256, 2) void mlp_k(
    const float* __restrict__ desc,
    const float* __restrict__ b1g,
    const float* __restrict__ b2g,
    const float* __restrict__ W3,
    const float* __restrict__ b3,
    const int* __restrict__ hdr,
    const int* __restrict__ sorted,
    const unsigned short* __restrict__ w1s,
    const unsigned short* __restrict__ w2s,
    float* __restrict__ out)
{
    __shared__ __align__(16) char buf[2][32768];  // x bf16 [64][512B] swizzled; h1 in-place
    __shared__ float part[4][64];

    const int tid  = threadIdx.x;
    const int lane = tid & 63;
    const int w    = tid >> 6;
    const int slot = tid >> 2;    // atom slot 0..63 (staging identity)
    const int q4   = tid & 3;     // quarter of the descriptor row

    const int total = hdr[16];
    int tile = blockIdx.x;
    if (tile >= total) return;

#define TILEINFO(TL, T, CNT, BASE, AST)                          \
    {                                                            \
        T = 3;                                                   \
        if      ((TL) < hdr[13]) T = 0;                          \
        else if ((TL) < hdr[14]) T = 1;                          \
        else if ((TL) < hdr[15]) T = 2;                          \
        CNT = hdr[T]; BASE = hdr[8 + T];                         \
        AST = ((TL) - hdr[12 + T]) * 64;                         \
    }

    float4 xr[16];

    // ---- prologue: stage first tile into buf[0]
    {
        int t0, cnt0, base0, as0;
        TILEINFO(tile, t0, cnt0, base0, as0);
        const int gg  = as0 + slot;
        const int idx = (gg < cnt0) ? sorted[base0 + gg] : 0;
        const float* row = desc + (size_t)idx * 256;
#pragma unroll
        for (int i = 0; i < 16; ++i)
            xr[i] = *(const float4*)(row + (q4 + i * 4) * 4);
#pragma unroll
        for (int i = 0; i < 16; ++i) {
            const int f = q4 + i * 4;
            unsigned short h4[4];
            h4[0] = f2bf(xr[i].x); h4[1] = f2bf(xr[i].y);
            h4[2] = f2bf(xr[i].z); h4[3] = f2bf(xr[i].w);
            const int off = slot * 512 + ((f * 8) ^ ((slot & 7) << 4));
            *(ushort4*)(buf[0] + off) = *(ushort4*)h4;
        }
    }
    __syncthreads();

    for (int k = 0;; ++k) {
        const int cur = k & 1;
        const int nxt = tile + MLPGRID;
        const bool has_next = (nxt < total);

        // ---- issue next tile's x loads (in flight across the whole compute)
        if (has_next) {
            int tn, cntn, basen, asn;
            TILEINFO(nxt, tn, cntn, basen, asn);
            const int gg  = asn + slot;
            const int idx = (gg < cntn) ? sorted[basen + gg] : 0;
            const float* row = desc + (size_t)idx * 256;
#pragma unroll
            for (int i = 0; i < 16; ++i)
                xr[i] = *(const float4*)(row + (q4 + i * 4) * 4);
        }

        // ---- compute current tile from buf[cur]
        int t, cnt, base, astart;
        TILEINFO(tile, t, cnt, base, astart);
        const unsigned short* w1t = w1s + (size_t)t * (16 * 8 * 512);
        const unsigned short* w2t = w2s + (size_t)t * (16 * 8 * 512);
        const char* cb = buf[cur];

        // L1: C1[h][atom]; wave owns h-tiles w*4..w*4+3
        f32x4 acc[4][4];
#pragma unroll
        for (int q = 0; q < 4; ++q)
#pragma unroll
            for (int nt = 0; nt < 4; ++nt)
                acc[q][nt] = (f32x4){0.f, 0.f, 0.f, 0.f};

#pragma unroll
        for (int ks = 0; ks < 8; ++ks) {
            short8 af[4];
#pragma unroll
            for (int q = 0; q < 4; ++q)
                af[q] = *(const short8*)(w1t + ((size_t)((w * 4 + q) * 8 + ks)) * 512 + lane * 8);
            short8 bh[4];
            const int colb = ks * 64 + ((lane >> 4) << 4);
#pragma unroll
            for (int nt = 0; nt < 4; ++nt) {
                const int row = nt * 16 + (lane & 15);
                const int off = row * 512 + (colb ^ ((row & 7) << 4));
                bh[nt] = *(const short8*)(cb + off);
            }
#pragma unroll
            for (int q = 0; q < 4; ++q)
#pragma unroll
                for (int nt = 0; nt < 4; ++nt)
                    acc[q][nt] = __builtin_amdgcn_mfma_f32_16x16x32_bf16(af[q], bh[nt], acc[q][nt], 0, 0, 0);
        }
        __syncthreads();   // all waves done reading x from buf[cur]

        // ep1: bias + tanh -> bf16 h1 into buf[cur]
        {
            char* hb = buf[cur];
#pragma unroll
            for (int q = 0; q < 4; ++q) {
                const int h0 = (w * 4 + q) * 16 + ((lane >> 4) << 2);
                const float4 bb = *(const float4*)(b1g + t * 256 + h0);
#pragma unroll
                for (int nt = 0; nt < 4; ++nt) {
                    const int atom = nt * 16 + (lane & 15);
                    unsigned short h4[4];
                    h4[0] = f2bf(fast_tanh(acc[q][nt][0] + bb.x));
                    h4[1] = f2bf(fast_tanh(acc[q][nt][1] + bb.y));
                    h4[2] = f2bf(fast_tanh(acc[q][nt][2] + bb.z));
                    h4[3] = f2bf(fast_tanh(acc[q][nt][3] + bb.w));
                    const int off = atom * 512 + ((h0 * 2) ^ ((atom & 7) << 4));
                    *(ushort4*)(hb + off) = *(ushort4*)h4;
                }
            }
        }
        __syncthreads();   // h1 fully written

        // L2: C2[atom][kout]; wave owns kout-tiles w*4..w*4+3
        f32x4 acc2[4][4];
#pragma unroll
        for (int mt = 0; mt < 4; ++mt)
#pragma unroll
            for (int q = 0; q < 4; ++q)
                acc2[mt][q] = (f32x4){0.f, 0.f, 0.f, 0.f};

#pragma unroll
        for (int ks = 0; ks < 8; ++ks) {
            short8 bw[4];
#pragma unroll
            for (int q = 0; q < 4; ++q)
                bw[q] = *(const short8*)(w2t + ((size_t)((w * 4 + q) * 8 + ks)) * 512 + lane * 8);
            short8 ah[4];
            const int colb = ks * 64 + ((lane >> 4) << 4);
#pragma unroll
            for (int mt = 0; mt < 4; ++mt) {
                const int row = mt * 16 + (lane & 15);
                const int off = row * 512 + (colb ^ ((row & 7) << 4));
                ah[mt] = *(const short8*)(cb + off);
            }
#pragma unroll
            for (int mt = 0; mt < 4; ++mt)
#pragma unroll
                for (int q = 0; q < 4; ++q)
                    acc2[mt][q] = __builtin_amdgcn_mfma_f32_16x16x32_bf16(ah[mt], bw[q], acc2[mt][q], 0, 0, 0);
        }

        // L3: fp32 dot with W3 over this wave's 64 kout columns
        float psum[4][4];
#pragma unroll
        for (int mt = 0; mt < 4; ++mt)
#pragma unroll
            for (int r = 0; r < 4; ++r)
                psum[mt][r] = 0.f;

#pragma unroll
        for (int q = 0; q < 4; ++q) {
            const int kout = (w * 4 + q) * 16 + (lane & 15);
            const float w3v = W3[t * 256 + kout];
            const float b2v = b2g[t * 256 + kout];
#pragma unroll
            for (int mt = 0; mt < 4; ++mt)
#pragma unroll
                for (int r = 0; r < 4; ++r)
                    psum[mt][r] += fast_tanh(acc2[mt][q][r] + b2v) * w3v;
        }
#pragma unroll
        for (int m = 1; m <= 8; m <<= 1)
#pragma unroll
            for (int mt = 0; mt < 4; ++mt)
#pragma unroll
                for (int r = 0; r < 4; ++r)
                    psum[mt][r] += __shfl_xor(psum[mt][r], m, 64);

        if ((lane & 15) == 0) {
            const int gq = lane >> 4;
#pragma unroll
            for (int mt = 0; mt < 4; ++mt)
#pragma unroll
                for (int r = 0; r < 4; ++r)
                    part[w][mt * 16 + gq * 4 + r] = psum[mt][r];
        }
        __syncthreads();   // partials ready

        if (tid < 64) {
            const int gg = astart + tid;
            if (gg < cnt) {
                float v = part[0][tid] + part[1][tid] + part[2][tid] + part[3][tid] + b3[t];
                out[sorted[base + gg]] = v;
            }
        }

        // ---- write next tile's x (loads complete by first use) into buf[cur^1]
        if (has_next) {
            char* nb = buf[cur ^ 1];
#pragma unroll
            for (int i = 0; i < 16; ++i) {
                const int f = q4 + i * 4;
                unsigned short h4[4];
                h4[0] = f2bf(xr[i].x); h4[1] = f2bf(xr[i].y);
                h4[2] = f2bf(xr[i].z); h4[3] = f2bf(xr[i].w);
                const int off = slot * 512 + ((f * 8) ^ ((slot & 7) << 4));
                *(ushort4*)(nb + off) = *(ushort4*)h4;
            }
        }
        __syncthreads();   // next buffer staged; part[] safe to reuse

        if (!has_next) break;
        tile = nxt;
    }
#undef TILEINFO
}

extern "C" void kernel_launch(void* const* d_in, const int* in_sizes, int n_in,
                              void* d_out, int out_size, void* d_ws, size_t ws_size,
                              hipStream_t stream) {
    const float* desc = (const float*)d_in[0];
    const int*   elems = (const int*)d_in[1];
    const float* W1 = (const float*)d_in[2];
    const float* b1 = (const float*)d_in[3];
    const float* W2 = (const float*)d_in[4];
    const float* b2 = (const float*)d_in[5];
    const float* W3 = (const float*)d_in[6];
    const float* b3 = (const float*)d_in[7];
    float* out = (float*)d_out;
    const int n = in_sizes[1];   // N_ATOMS

    char* ws = (char*)d_ws;
    int* hdr    = (int*)ws;                       // 32 ints
    int* counts = (int*)(ws + 128);               // 4*NPB ints
    int* cursor = (int*)(ws + 128 + 4 * NPB * 4); // 4*NPB ints
    int* sorted = (int*)(ws + 128 + 8 * NPB * 4);
    unsigned short* w1s = (unsigned short*)((char*)sorted + (size_t)n * 4);
    unsigned short* w2s = w1s + (size_t)4 * 16 * 8 * 512;

    const int chunk = (n + NPB - 1) / NPB;

    count_k<<<NPB, 256, 0, stream>>>(elems, n, chunk, counts);
    prefix_k<<<1, 64, 0, stream>>>(counts, cursor, hdr);
    scatter_k<<<NPB, 256, 0, stream>>>(elems, n, chunk, cursor, sorted);
    wconv_k<<<256, 256, 0, stream>>>(W1, W2, w1s, w2s);

    mlp_k<<<MLPGRID, 256, 0, stream>>>(desc, b1, b2, W3, b3,
                                       hdr, sorted, w1s, w2s, out);
}

// Round 14
// 146.487 us; speedup vs baseline: 1.5587x; 1.2280x over previous
//
#include <hip/hip_runtime.h>
#include <hip/hip_bf16.h>
#include <stdint.h>

// ---------------------------------------------------------------------------
// Per-type MLP dispatch (ElemwiseModels): out[n] = MLP_{elems[n]}(desc[n])
//   L1: h1 = tanh(x @ W1[t] + b1[t])     x:256 -> 256
//   L2: h2 = tanh(h1 @ W2[t] + b2[t])    256 -> 256
//   L3: out = h2 . W3[t] + b3[t]         256 -> 1
// r14: persistent 1-block/CU, double-buffered ASYNC DMA staging:
//   - x staged fp32 via __builtin_amdgcn_global_load_lds (zero VGPRs, no
//     spill possible; issued one full tile ahead)
//   - LDS chunk stride 1088 (+64B pad) + source-side XOR swizzle -> <=2-way
//     bank conflicts on frag reads (both-sides-or-neither, m173 pattern)
//   - fp32->bf16 conversion folded into the L1 frag read
//   - block-cooperative L1/L2 fragments + L3 mapping: r7/r11-validated
// ---------------------------------------------------------------------------

typedef __attribute__((ext_vector_type(8))) short short8;   // 8 x bf16 frag
typedef __attribute__((ext_vector_type(4))) float f32x4;    // MFMA acc

#define NPB 256          // partition blocks
#define NTY 4            // types
#define MLPGRID 256      // persistent mlp blocks (1 per CU)
#define XBUF_BYTES 69632 // 4 groups * 16 chunks * 1088

typedef __attribute__((address_space(3))) void lds_void;
typedef __attribute__((address_space(1))) const void glb_void;

__device__ __forceinline__ unsigned short f2bf(float f) {
    union { float f; uint32_t u; } v; v.f = f;
    uint32_t u = v.u;
    uint32_t r = (u + 0x7FFFu + ((u >> 16) & 1u)) >> 16;   // RN-even
    return (unsigned short)r;
}
__device__ __forceinline__ float fast_tanh(float x) {
    x = fminf(fmaxf(x, -10.0f), 10.0f);
    float e = __expf(2.0f * x);
    return (e - 1.0f) * __builtin_amdgcn_rcpf(e + 1.0f);
}

// ---------------- ws layout -------------------------------------------------
// hdr   (32 ints @ 0):      [0..3] counts, [8..11] base, [12..15] tilebase, [16] total tiles
// counts(4*NPB ints @128);  cursor(4*NPB ints);  sorted(n ints);  w1s/w2s (bf16)
// ---------------------------------------------------------------------------

__global__ void count_k(const int* __restrict__ elems, int n, int chunk,
                        int* __restrict__ counts) {
    __shared__ int h[NTY];
    if (threadIdx.x < NTY) h[threadIdx.x] = 0;
    __syncthreads();
    const int start = blockIdx.x * chunk;
    const int end   = min(start + chunk, n);
    for (int i = start + threadIdx.x; i < end; i += blockDim.x)
        atomicAdd(&h[elems[i]], 1);
    __syncthreads();
    if (threadIdx.x < NTY) counts[threadIdx.x * NPB + blockIdx.x] = h[threadIdx.x];
}

__global__ void prefix_k(const int* __restrict__ counts,
                         int* __restrict__ cursor, int* __restrict__ hdr) {
    __shared__ int tot[NTY];
    const int t = threadIdx.x;
    if (t < NTY) {
        int s = 0;
        for (int b = 0; b < NPB; ++b) s += counts[t * NPB + b];
        tot[t] = s;
    }
    __syncthreads();
    if (t == 0) {
        int b = 0, tb = 0;
        for (int ty = 0; ty < NTY; ++ty) {
            hdr[ty]      = tot[ty];
            hdr[8 + ty]  = b;
            hdr[12 + ty] = tb;
            b  += tot[ty];
            tb += (tot[ty] + 63) >> 6;
        }
        hdr[16] = tb;
    }
    __syncthreads();
    if (t < NTY) {
        int run = hdr[8 + t];
        for (int b = 0; b < NPB; ++b) {
            cursor[t * NPB + b] = run;
            run += counts[t * NPB + b];
        }
    }
}

__global__ void scatter_k(const int* __restrict__ elems, int n, int chunk,
                          const int* __restrict__ cursor, int* __restrict__ sorted) {
    __shared__ int cur[NTY];
    if (threadIdx.x < NTY) cur[threadIdx.x] = cursor[threadIdx.x * NPB + blockIdx.x];
    __syncthreads();
    const int start = blockIdx.x * chunk;
    const int end   = min(start + chunk, n);
    for (int i = start + threadIdx.x; i < end; i += blockDim.x) {
        int ty  = elems[i];
        int pos = atomicAdd(&cur[ty], 1);   // LDS atomic: block-local
        sorted[pos] = i;
    }
}

// Pre-swizzle W1,W2 (fp32 [t][din][dout]) into bf16 MFMA-frag order:
// frag(t,tile,ks): 64 lanes x 16B contiguous; lane l elem j =
//   W[t][ks*32 + (l>>4)*8 + j][tile*16 + (l&15)]
__global__ void wconv_k(const float* __restrict__ W1, const float* __restrict__ W2,
                        unsigned short* __restrict__ w1s, unsigned short* __restrict__ w2s) {
    int gid  = blockIdx.x * blockDim.x + threadIdx.x;   // 0..65535
    int lane = gid & 63;
    int ks   = (gid >> 6) & 7;
    int tile = (gid >> 9) & 15;
    int t    = (gid >> 13) & 3;
    int layer = gid >> 15;
    const float* W = layer ? W2 : W1;
    unsigned short* o = layer ? w2s : w1s;
    int dbase = ks * 32 + ((lane >> 4) << 3);
    int col   = tile * 16 + (lane & 15);
    unsigned short v[8];
#pragma unroll
    for (int j = 0; j < 8; ++j)
        v[j] = f2bf(W[(size_t)t * 65536 + (size_t)(dbase + j) * 256 + col]);
    unsigned short* dst = o + ((size_t)(t * 16 + tile) * 8 + ks) * 512 + lane * 8;
    *(short8*)dst = *(short8*)v;
}

// read bf16 B-frag (8 k-values) for atom-row a, fp32 byte offset c0 in row,
// from the DMA-staged swizzled x buffer; converts fp32->bf16 on the fly.
__device__ __forceinline__ short8 read_xfrag(const char* cb, int a, int c0) {
    const int swz = (a & 7) << 4;
    const int cs0 = c0 ^ swz;
    const int cs1 = (c0 + 16) ^ swz;
    const int ab  = (a >> 4) * 17408 + (a & 15) * 64;
    const float4 f0 = *(const float4*)(cb + ab + (cs0 >> 6) * 1088 + (cs0 & 0x30));
    const float4 f1 = *(const float4*)(cb + ab + (cs1 >> 6) * 1088 + (cs1 & 0x30));
    union { short8 s; __hip_bfloat162 h[4]; } u;
    u.h[0] = __float22bfloat162_rn(make_float2(f0.x, f0.y));
    u.h[1] = __float22bfloat162_rn(make_float2(f0.z, f0.w));
    u.h[2] = __float22bfloat162_rn(make_float2(f1.x, f1.y));
    u.h[3] = __float22bfloat162_rn(make_float2(f1.z, f1.w));
    return u.s;
}

// ---------------------------------------------------------------------------
// Persistent main kernel: 256 blocks (1/CU), tiles bid, bid+256, ...
// LDS: xbuf[2][68KB] fp32 DMA-staged (h1 bf16 reuses retiring buffer) + part.
// ---------------------------------------------------------------------------
__global__ __launch_bounds__(256, 1) void mlp_k(
    const float* __restrict__ desc,
    const float* __restrict__ b1g,
    const float* __restrict__ b2g,
    const float* __restrict__ W3,
    const float* __restrict__ b3,
    const int* __restrict__ hdr,
    const int* __restrict__ sorted,
    const unsigned short* __restrict__ w1s,
    const unsigned short* __restrict__ w2s,
    float* __restrict__ out)
{
    __shared__ __align__(16) char buf[2][XBUF_BYTES];
    __shared__ float part[4][64];

    const int tid  = threadIdx.x;
    const int lane = tid & 63;
    const int w    = tid >> 6;
    const int g    = lane >> 4;       // k-group 0..3 (frag reads)
    const int sa   = lane >> 2;       // staging: atom within wave 0..15
    const int qq   = lane & 3;        // staging: 16B quarter of 64B chunk
    const int sswz = (sa & 7) << 4;   // staging source swizzle

    const int total = hdr[16];
    int tile = blockIdx.x;
    if (tile >= total) return;

#define TILEINFO(TL, T, CNT, BASE, AST)                          \
    {                                                            \
        T = 3;                                                   \
        if      ((TL) < hdr[13]) T = 0;                          \
        else if ((TL) < hdr[14]) T = 1;                          \
        else if ((TL) < hdr[15]) T = 2;                          \
        CNT = hdr[T]; BASE = hdr[8 + T];                         \
        AST = ((TL) - hdr[12 + T]) * 64;                         \
    }

#define STAGE(TL, BP)                                                         \
    {                                                                         \
        int st_, sc_, sb_, sa_;                                               \
        TILEINFO(TL, st_, sc_, sb_, sa_);                                     \
        const int gg_  = sa_ + w * 16 + sa;                                   \
        const int idx_ = (gg_ < sc_) ? sorted[sb_ + gg_] : 0;                 \
        const float* rowp_ = desc + (size_t)idx_ * 256;                       \
        _Pragma("unroll")                                                     \
        for (int i_ = 0; i_ < 16; ++i_) {                                     \
            const float* src_ = rowp_ + (((i_ * 64 + qq * 16) ^ sswz) >> 2);  \
            char* dst_ = (BP) + w * 17408 + i_ * 1088;                        \
            __builtin_amdgcn_global_load_lds((glb_void*)src_,                 \
                                             (lds_void*)dst_, 16, 0, 0);      \
        }                                                                     \
    }

    // ---- prologue: DMA first tile into buf[0]
    STAGE(tile, buf[0]);

    for (int k = 0;; ++k) {
        const int cur = k & 1;
        const int nxt = tile + MLPGRID;
        const bool has_next = (nxt < total);

        // buf[cur]'s DMA (issued one tile ago) must be complete everywhere
        asm volatile("s_waitcnt vmcnt(0)" ::: "memory");
        __syncthreads();

        // issue next tile's DMA into the other buffer (in flight all tile long)
        if (has_next) STAGE(nxt, buf[cur ^ 1]);

        int t, cnt, base, astart;
        TILEINFO(tile, t, cnt, base, astart);
        const unsigned short* w1t = w1s + (size_t)t * (16 * 8 * 512);
        const unsigned short* w2t = w2s + (size_t)t * (16 * 8 * 512);
        const char* cb = buf[cur];

        // ---- L1: C1[h][atom]; wave owns h-tiles w*4..w*4+3
        f32x4 acc[4][4];
#pragma unroll
        for (int q = 0; q < 4; ++q)
#pragma unroll
            for (int nt = 0; nt < 4; ++nt)
                acc[q][nt] = (f32x4){0.f, 0.f, 0.f, 0.f};

#pragma unroll
        for (int ks = 0; ks < 8; ++ks) {
            short8 af[4];
#pragma unroll
            for (int q = 0; q < 4; ++q)
                af[q] = *(const short8*)(w1t + ((size_t)((w * 4 + q) * 8 + ks)) * 512 + lane * 8);
            short8 bh[4];
            const int c0 = ks * 128 + g * 32;   // fp32 byte offset in row
#pragma unroll
            for (int nt = 0; nt < 4; ++nt)
                bh[nt] = read_xfrag(cb, nt * 16 + (lane & 15), c0);
#pragma unroll
            for (int q = 0; q < 4; ++q)
#pragma unroll
                for (int nt = 0; nt < 4; ++nt)
                    acc[q][nt] = __builtin_amdgcn_mfma_f32_16x16x32_bf16(af[q], bh[nt], acc[q][nt], 0, 0, 0);
        }
        __syncthreads();   // all waves done reading x from buf[cur]

        // ---- ep1: bias + tanh -> bf16 h1 into buf[cur][0..32K)
        {
            char* hb = buf[cur];
#pragma unroll
            for (int q = 0; q < 4; ++q) {
                const int h0 = (w * 4 + q) * 16 + ((lane >> 4) << 2);
                const float4 bb = *(const float4*)(b1g + t * 256 + h0);
#pragma unroll
                for (int nt = 0; nt < 4; ++nt) {
                    const int atom = nt * 16 + (lane & 15);
                    unsigned short h4[4];
                    h4[0] = f2bf(fast_tanh(acc[q][nt][0] + bb.x));
                    h4[1] = f2bf(fast_tanh(acc[q][nt][1] + bb.y));
                    h4[2] = f2bf(fast_tanh(acc[q][nt][2] + bb.z));
                    h4[3] = f2bf(fast_tanh(acc[q][nt][3] + bb.w));
                    const int off = atom * 512 + ((h0 * 2) ^ ((atom & 7) << 4));
                    *(ushort4*)(hb + off) = *(ushort4*)h4;
                }
            }
        }
        __syncthreads();   // h1 fully written

        // ---- L2: C2[atom][kout]; wave owns kout-tiles w*4..w*4+3
        f32x4 acc2[4][4];
#pragma unroll
        for (int mt = 0; mt < 4; ++mt)
#pragma unroll
            for (int q = 0; q < 4; ++q)
                acc2[mt][q] = (f32x4){0.f, 0.f, 0.f, 0.f};

#pragma unroll
        for (int ks = 0; ks < 8; ++ks) {
            short8 bw[4];
#pragma unroll
            for (int q = 0; q < 4; ++q)
                bw[q] = *(const short8*)(w2t + ((size_t)((w * 4 + q) * 8 + ks)) * 512 + lane * 8);
            short8 ah[4];
            const int colb = ks * 64 + ((lane >> 4) << 4);
#pragma unroll
            for (int mt = 0; mt < 4; ++mt) {
                const int row = mt * 16 + (lane & 15);
                const int off = row * 512 + (colb ^ ((row & 7) << 4));
                ah[mt] = *(const short8*)(cb + off);
            }
#pragma unroll
            for (int mt = 0; mt < 4; ++mt)
#pragma unroll
                for (int q = 0; q < 4; ++q)
                    acc2[mt][q] = __builtin_amdgcn_mfma_f32_16x16x32_bf16(ah[mt], bw[q], acc2[mt][q], 0, 0, 0);
        }

        // ---- L3: fp32 dot with W3 over this wave's 64 kout columns
        float psum[4][4];
#pragma unroll
        for (int mt = 0; mt < 4; ++mt)
#pragma unroll
            for (int r = 0; r < 4; ++r)
                psum[mt][r] = 0.f;

#pragma unroll
        for (int q = 0; q < 4; ++q) {
            const int kout = (w * 4 + q) * 16 + (lane & 15);
            const float w3v = W3[t * 256 + kout];
            const float b2v = b2g[t * 256 + kout];
#pragma unroll
            for (int mt = 0; mt < 4; ++mt)
#pragma unroll
                for (int r = 0; r < 4; ++r)
                    psum[mt][r] += fast_tanh(acc2[mt][q][r] + b2v) * w3v;
        }
#pragma unroll
        for (int m = 1; m <= 8; m <<= 1)
#pragma unroll
            for (int mt = 0; mt < 4; ++mt)
#pragma unroll
                for (int r = 0; r < 4; ++r)
                    psum[mt][r] += __shfl_xor(psum[mt][r], m, 64);

        if ((lane & 15) == 0) {
            const int gq = lane >> 4;
#pragma unroll
            for (int mt = 0; mt < 4; ++mt)
#pragma unroll
                for (int r = 0; r < 4; ++r)
                    part[w][mt * 16 + gq * 4 + r] = psum[mt][r];
        }
        __syncthreads();   // partials ready (also isolates part[] reuse)

        if (tid < 64) {
            const int gg = astart + tid;
            if (gg < cnt) {
                float v = part[0][tid] + part[1][tid] + part[2][tid] + part[3][tid] + b3[t];
                out[sorted[base + gg]] = v;
            }
        }

        if (!has_next) break;
        tile = nxt;
    }
#undef STAGE
#undef TILEINFO
}

extern "C" void kernel_launch(void* const* d_in, const int* in_sizes, int n_in,
                              void* d_out, int out_size, void* d_ws, size_t ws_size,
                              hipStream_t stream) {
    const float* desc = (const float*)d_in[0];
    const int*   elems = (const int*)d_in[1];
    const float* W1 = (const float*)d_in[2];
    const float* b1 = (const float*)d_in[3];
    const float* W2 = (const float*)d_in[4];
    const float* b2 = (const float*)d_in[5];
    const float* W3 = (const float*)d_in[6];
    const float* b3 = (const float*)d_in[7];
    float* out = (float*)d_out;
    const int n = in_sizes[1];   // N_ATOMS

    char* ws = (char*)d_ws;
    int* hdr    = (int*)ws;                       // 32 ints
    int* counts = (int*)(ws + 128);               // 4*NPB ints
    int* cursor = (int*)(ws + 128 + 4 * NPB * 4); // 4*NPB ints
    int* sorted = (int*)(ws + 128 + 8 * NPB * 4);
    unsigned short* w1s = (unsigned short*)((char*)sorted + (size_t)n * 4);
    unsigned short* w2s = w1s + (size_t)4 * 16 * 8 * 512;

    const int chunk = (n + NPB - 1) / NPB;

    count_k<<<NPB, 256, 0, stream>>>(elems, n, chunk, counts);
    prefix_k<<<1, 64, 0, stream>>>(counts, cursor, hdr);
    scatter_k<<<NPB, 256, 0, stream>>>(elems, n, chunk, cursor, sorted);
    wconv_k<<<256, 256, 0, stream>>>(W1, W2, w1s, w2s);

    mlp_k<<<MLPGRID, 256, 0, stream>>>(desc, b1, b2, W3, b3,
                                       hdr, sorted, w1s, w2s, out);
}

// Round 15
// 111.932 us; speedup vs baseline: 2.0399x; 1.3087x over previous
//
#include <hip/hip_runtime.h>
#include <hip/hip_bf16.h>
#include <stdint.h>

// ---------------------------------------------------------------------------
// Per-type MLP dispatch (ElemwiseModels): out[n] = MLP_{elems[n]}(desc[n])
//   L1: h1 = tanh(x @ W1[t] + b1[t])     x:256 -> 256
//   L2: h2 = tanh(h1 @ W2[t] + b2[t])    256 -> 256
//   L3: out = h2 . W3[t] + b3[t]         256 -> 1
// r15: persistent TYPE-PINNED blocks, WEIGHTS HOISTED INTO REGISTERS.
//   - grid 256 = 64 blocks x 4 types; block strides its type's tiles by 64
//   - 512 threads / 8 waves (2 waves/SIMD, r7's best occupancy); wave owns
//     2 h-tiles (L1) + 2 kout-tiles (L2) -> weight frags = 128 VGPR, loaded
//     ONCE per block lifetime; zero weight traffic in the tile loop
//   - x staged fp32 by zero-VGPR __builtin_amdgcn_global_load_lds DMA,
//     double-buffered, source-XOR-swizzled (r14-validated); fp32->bf16
//     conversion folded into the L1 frag read
//   - fragment layouts + L3 mapping: r7/r11/r14-validated
// ---------------------------------------------------------------------------

typedef __attribute__((ext_vector_type(8))) short short8;   // 8 x bf16 frag
typedef __attribute__((ext_vector_type(4))) float f32x4;    // MFMA acc

#define NPB 256          // partition blocks
#define NTY 4            // types
#define XBUF_BYTES 69632 // 4 groups * 16 chunks * 1088

typedef __attribute__((address_space(3))) void lds_void;
typedef __attribute__((address_space(1))) const void glb_void;

__device__ __forceinline__ unsigned short f2bf(float f) {
    union { float f; uint32_t u; } v; v.f = f;
    uint32_t u = v.u;
    uint32_t r = (u + 0x7FFFu + ((u >> 16) & 1u)) >> 16;   // RN-even
    return (unsigned short)r;
}
__device__ __forceinline__ float fast_tanh(float x) {
    x = fminf(fmaxf(x, -10.0f), 10.0f);
    float e = __expf(2.0f * x);
    return (e - 1.0f) * __builtin_amdgcn_rcpf(e + 1.0f);
}

// ---------------- ws layout -------------------------------------------------
// hdr   (32 ints @ 0):      [0..3] counts, [8..11] base, [12..15] tilebase, [16] total tiles
// counts(4*NPB ints @128);  cursor(4*NPB ints);  sorted(n ints);  w1s/w2s (bf16)
// ---------------------------------------------------------------------------

__global__ void count_k(const int* __restrict__ elems, int n, int chunk,
                        int* __restrict__ counts) {
    __shared__ int h[NTY];
    if (threadIdx.x < NTY) h[threadIdx.x] = 0;
    __syncthreads();
    const int start = blockIdx.x * chunk;
    const int end   = min(start + chunk, n);
    for (int i = start + threadIdx.x; i < end; i += blockDim.x)
        atomicAdd(&h[elems[i]], 1);
    __syncthreads();
    if (threadIdx.x < NTY) counts[threadIdx.x * NPB + blockIdx.x] = h[threadIdx.x];
}

__global__ void prefix_k(const int* __restrict__ counts,
                         int* __restrict__ cursor, int* __restrict__ hdr) {
    __shared__ int tot[NTY];
    const int t = threadIdx.x;
    if (t < NTY) {
        int s = 0;
        for (int b = 0; b < NPB; ++b) s += counts[t * NPB + b];
        tot[t] = s;
    }
    __syncthreads();
    if (t == 0) {
        int b = 0, tb = 0;
        for (int ty = 0; ty < NTY; ++ty) {
            hdr[ty]      = tot[ty];
            hdr[8 + ty]  = b;
            hdr[12 + ty] = tb;
            b  += tot[ty];
            tb += (tot[ty] + 63) >> 6;
        }
        hdr[16] = tb;
    }
    __syncthreads();
    if (t < NTY) {
        int run = hdr[8 + t];
        for (int b = 0; b < NPB; ++b) {
            cursor[t * NPB + b] = run;
            run += counts[t * NPB + b];
        }
    }
}

__global__ void scatter_k(const int* __restrict__ elems, int n, int chunk,
                          const int* __restrict__ cursor, int* __restrict__ sorted) {
    __shared__ int cur[NTY];
    if (threadIdx.x < NTY) cur[threadIdx.x] = cursor[threadIdx.x * NPB + blockIdx.x];
    __syncthreads();
    const int start = blockIdx.x * chunk;
    const int end   = min(start + chunk, n);
    for (int i = start + threadIdx.x; i < end; i += blockDim.x) {
        int ty  = elems[i];
        int pos = atomicAdd(&cur[ty], 1);   // LDS atomic: block-local
        sorted[pos] = i;
    }
}

// Pre-swizzle W1,W2 (fp32 [t][din][dout]) into bf16 MFMA-frag order:
// frag(t,tile,ks): 64 lanes x 16B contiguous; lane l elem j =
//   W[t][ks*32 + (l>>4)*8 + j][tile*16 + (l&15)]
__global__ void wconv_k(const float* __restrict__ W1, const float* __restrict__ W2,
                        unsigned short* __restrict__ w1s, unsigned short* __restrict__ w2s) {
    int gid  = blockIdx.x * blockDim.x + threadIdx.x;   // 0..65535
    int lane = gid & 63;
    int ks   = (gid >> 6) & 7;
    int tile = (gid >> 9) & 15;
    int t    = (gid >> 13) & 3;
    int layer = gid >> 15;
    const float* W = layer ? W2 : W1;
    unsigned short* o = layer ? w2s : w1s;
    int dbase = ks * 32 + ((lane >> 4) << 3);
    int col   = tile * 16 + (lane & 15);
    unsigned short v[8];
#pragma unroll
    for (int j = 0; j < 8; ++j)
        v[j] = f2bf(W[(size_t)t * 65536 + (size_t)(dbase + j) * 256 + col]);
    unsigned short* dst = o + ((size_t)(t * 16 + tile) * 8 + ks) * 512 + lane * 8;
    *(short8*)dst = *(short8*)v;
}

// read bf16 B-frag (8 k-values) for atom-row a, fp32 byte offset c0 in row,
// from the DMA-staged swizzled x buffer; converts fp32->bf16 on the fly.
__device__ __forceinline__ short8 read_xfrag(const char* cb, int a, int c0) {
    const int swz = (a & 7) << 4;
    const int cs0 = c0 ^ swz;
    const int cs1 = (c0 + 16) ^ swz;
    const int ab  = (a >> 4) * 17408 + (a & 15) * 64;
    const float4 f0 = *(const float4*)(cb + ab + (cs0 >> 6) * 1088 + (cs0 & 0x30));
    const float4 f1 = *(const float4*)(cb + ab + (cs1 >> 6) * 1088 + (cs1 & 0x30));
    union { short8 s; __hip_bfloat162 h[4]; } u;
    u.h[0] = __float22bfloat162_rn(make_float2(f0.x, f0.y));
    u.h[1] = __float22bfloat162_rn(make_float2(f0.z, f0.w));
    u.h[2] = __float22bfloat162_rn(make_float2(f1.x, f1.y));
    u.h[3] = __float22bfloat162_rn(make_float2(f1.z, f1.w));
    return u.s;
}

// ---------------------------------------------------------------------------
// Persistent type-pinned main kernel: 256 blocks (64 per type), 512 threads.
// LDS: 2 x 68KB DMA x-buffers (h1 bf16 reuses retiring buffer) + part.
// ---------------------------------------------------------------------------
__global__ __launch_bounds__(512, 2) void mlp_k(
    const float* __restrict__ desc,
    const float* __restrict__ b1g,
    const float* __restrict__ b2g,
    const float* __restrict__ W3,
    const float* __restrict__ b3,
    const int* __restrict__ hdr,
    const int* __restrict__ sorted,
    const unsigned short* __restrict__ w1s,
    const unsigned short* __restrict__ w2s,
    float* __restrict__ out)
{
    __shared__ __align__(16) char buf[2][XBUF_BYTES];
    __shared__ float part[8][64];

    const int tid  = threadIdx.x;
    const int lane = tid & 63;
    const int w    = tid >> 6;        // wave 0..7
    const int g    = lane >> 4;       // k-group 0..3 (frag reads)
    const int a16  = lane & 15;
    // staging ids: wave (w&3) stages group (w&3); (w>>2) picks chunk half
    const int sa   = lane >> 2;       // atom within group 0..15
    const int qq   = lane & 3;        // 16B quarter of 64B chunk
    const int gw   = w & 3;           // staged group
    const int ch   = w >> 2;          // chunk half 0/1
    const int sswz = (sa & 7) << 4;

    const int t     = blockIdx.x >> 6;     // type (block pinned)
    const int bslot = blockIdx.x & 63;
    const int cnt   = hdr[t];
    const int base  = hdr[8 + t];
    const int ntile = (cnt + 63) >> 6;
    if (bslot >= ntile) return;

#define STAGE(J, BP)                                                          \
    {                                                                         \
        const int gg_  = (J) * 64 + gw * 16 + sa;                             \
        const int idx_ = (gg_ < cnt) ? sorted[base + gg_] : 0;                \
        const float* rowp_ = desc + (size_t)idx_ * 256;                       \
        _Pragma("unroll")                                                     \
        for (int i_ = 0; i_ < 8; ++i_) {                                      \
            const int c_ = ch * 8 + i_;                                       \
            const float* src_ = rowp_ + (((c_ * 64 + qq * 16) ^ sswz) >> 2);  \
            char* dst_ = (BP) + gw * 17408 + c_ * 1088;                       \
            __builtin_amdgcn_global_load_lds((glb_void*)src_,                 \
                                             (lds_void*)dst_, 16, 0, 0);      \
        }                                                                     \
    }

    // ---- prologue: DMA first tile, then hoist this wave's weights into regs
    int j = bslot;
    STAGE(j, buf[0]);

    const unsigned short* w1t = w1s + (size_t)t * (16 * 8 * 512);
    const unsigned short* w2t = w2s + (size_t)t * (16 * 8 * 512);
    short8 wf1[2][8], wf2[2][8];      // 128 VGPR, held for block lifetime
#pragma unroll
    for (int q = 0; q < 2; ++q)
#pragma unroll
        for (int ks = 0; ks < 8; ++ks) {
            wf1[q][ks] = *(const short8*)(w1t + ((size_t)((w * 2 + q) * 8 + ks)) * 512 + lane * 8);
            wf2[q][ks] = *(const short8*)(w2t + ((size_t)((w * 2 + q) * 8 + ks)) * 512 + lane * 8);
        }
    float4 bq[2];
    float  w3r[2], b2r[2];
#pragma unroll
    for (int q = 0; q < 2; ++q) {
        bq[q]  = *(const float4*)(b1g + t * 256 + (w * 2 + q) * 16 + g * 4);
        const int kout = (w * 2 + q) * 16 + a16;
        w3r[q] = W3[t * 256 + kout];
        b2r[q] = b2g[t * 256 + kout];
    }
    const float b3v = b3[t];

    for (int k = 0;; ++k) {
        const int cur = k & 1;
        const int jn  = j + 64;
        const bool has_next = (jn < ntile);

        // buf[cur]'s DMA (issued one tile ago) must be complete everywhere
        asm volatile("s_waitcnt vmcnt(0)" ::: "memory");
        __syncthreads();

        // issue next tile's DMA into the other buffer
        if (has_next) STAGE(jn, buf[cur ^ 1]);

        const char* cb = buf[cur];

        // ---- L1: C1[h][atom]; wave owns h-tiles w*2, w*2+1
        f32x4 acc[2][4];
#pragma unroll
        for (int q = 0; q < 2; ++q)
#pragma unroll
            for (int nt = 0; nt < 4; ++nt)
                acc[q][nt] = (f32x4){0.f, 0.f, 0.f, 0.f};

#pragma unroll
        for (int ks = 0; ks < 8; ++ks) {
            short8 bh[4];
            const int c0 = ks * 128 + g * 32;   // fp32 byte offset in row
#pragma unroll
            for (int nt = 0; nt < 4; ++nt)
                bh[nt] = read_xfrag(cb, nt * 16 + a16, c0);
#pragma unroll
            for (int q = 0; q < 2; ++q)
#pragma unroll
                for (int nt = 0; nt < 4; ++nt)
                    acc[q][nt] = __builtin_amdgcn_mfma_f32_16x16x32_bf16(wf1[q][ks], bh[nt], acc[q][nt], 0, 0, 0);
        }
        __syncthreads();   // all waves done reading x from buf[cur]

        // ---- ep1: bias + tanh -> bf16 h1 into buf[cur][0..32K)
        {
            char* hb = buf[cur];
#pragma unroll
            for (int q = 0; q < 2; ++q) {
                const int h0 = (w * 2 + q) * 16 + g * 4;
#pragma unroll
                for (int nt = 0; nt < 4; ++nt) {
                    const int atom = nt * 16 + a16;
                    unsigned short h4[4];
                    h4[0] = f2bf(fast_tanh(acc[q][nt][0] + bq[q].x));
                    h4[1] = f2bf(fast_tanh(acc[q][nt][1] + bq[q].y));
                    h4[2] = f2bf(fast_tanh(acc[q][nt][2] + bq[q].z));
                    h4[3] = f2bf(fast_tanh(acc[q][nt][3] + bq[q].w));
                    const int off = atom * 512 + ((h0 * 2) ^ ((atom & 7) << 4));
                    *(ushort4*)(hb + off) = *(ushort4*)h4;
                }
            }
        }
        __syncthreads();   // h1 fully written

        // ---- L2: C2[atom][kout]; wave owns kout-tiles w*2, w*2+1
        f32x4 acc2[4][2];
#pragma unroll
        for (int mt = 0; mt < 4; ++mt)
#pragma unroll
            for (int q = 0; q < 2; ++q)
                acc2[mt][q] = (f32x4){0.f, 0.f, 0.f, 0.f};

#pragma unroll
        for (int ks = 0; ks < 8; ++ks) {
            short8 ah[4];
            const int colb = ks * 64 + g * 16;
#pragma unroll
            for (int mt = 0; mt < 4; ++mt) {
                const int row = mt * 16 + a16;
                const int off = row * 512 + (colb ^ ((row & 7) << 4));
                ah[mt] = *(const short8*)(cb + off);
            }
#pragma unroll
            for (int mt = 0; mt < 4; ++mt)
#pragma unroll
                for (int q = 0; q < 2; ++q)
                    acc2[mt][q] = __builtin_amdgcn_mfma_f32_16x16x32_bf16(ah[mt], wf2[q][ks], acc2[mt][q], 0, 0, 0);
        }

        // ---- L3: acc2[mt][q][r] = C2[atom=mt*16+g*4+r][kout=(w*2+q)*16+a16]
        float psum[4][4];
#pragma unroll
        for (int mt = 0; mt < 4; ++mt)
#pragma unroll
            for (int r = 0; r < 4; ++r)
                psum[mt][r] = 0.f;

#pragma unroll
        for (int q = 0; q < 2; ++q)
#pragma unroll
            for (int mt = 0; mt < 4; ++mt)
#pragma unroll
                for (int r = 0; r < 4; ++r)
                    psum[mt][r] += fast_tanh(acc2[mt][q][r] + b2r[q]) * w3r[q];

#pragma unroll
        for (int m = 1; m <= 8; m <<= 1)
#pragma unroll
            for (int mt = 0; mt < 4; ++mt)
#pragma unroll
                for (int r = 0; r < 4; ++r)
                    psum[mt][r] += __shfl_xor(psum[mt][r], m, 64);

        if (a16 == 0) {
#pragma unroll
            for (int mt = 0; mt < 4; ++mt)
#pragma unroll
                for (int r = 0; r < 4; ++r)
                    part[w][mt * 16 + g * 4 + r] = psum[mt][r];
        }
        __syncthreads();   // partials ready

        if (tid < 64) {
            const int gg = j * 64 + tid;
            if (gg < cnt) {
                float v = b3v;
#pragma unroll
                for (int ww = 0; ww < 8; ++ww) v += part[ww][tid];
                out[sorted[base + gg]] = v;
            }
        }

        if (!has_next) break;
        j = jn;
    }
#undef STAGE
}

extern "C" void kernel_launch(void* const* d_in, const int* in_sizes, int n_in,
                              void* d_out, int out_size, void* d_ws, size_t ws_size,
                              hipStream_t stream) {
    const float* desc = (const float*)d_in[0];
    const int*   elems = (const int*)d_in[1];
    const float* W1 = (const float*)d_in[2];
    const float* b1 = (const float*)d_in[3];
    const float* W2 = (const float*)d_in[4];
    const float* b2 = (const float*)d_in[5];
    const float* W3 = (const float*)d_in[6];
    const float* b3 = (const float*)d_in[7];
    float* out = (float*)d_out;
    const int n = in_sizes[1];   // N_ATOMS

    char* ws = (char*)d_ws;
    int* hdr    = (int*)ws;                       // 32 ints
    int* counts = (int*)(ws + 128);               // 4*NPB ints
    int* cursor = (int*)(ws + 128 + 4 * NPB * 4); // 4*NPB ints
    int* sorted = (int*)(ws + 128 + 8 * NPB * 4);
    unsigned short* w1s = (unsigned short*)((char*)sorted + (size_t)n * 4);
    unsigned short* w2s = w1s + (size_t)4 * 16 * 8 * 512;

    const int chunk = (n + NPB - 1) / NPB;

    count_k<<<NPB, 256, 0, stream>>>(elems, n, chunk, counts);
    prefix_k<<<1, 64, 0, stream>>>(counts, cursor, hdr);
    scatter_k<<<NPB, 256, 0, stream>>>(elems, n, chunk, cursor, sorted);
    wconv_k<<<256, 256, 0, stream>>>(W1, W2, w1s, w2s);

    mlp_k<<<NTY * 64, 512, 0, stream>>>(desc, b1, b2, W3, b3,
                                        hdr, sorted, w1s, w2s, out);
}